// Round 17
// baseline (154.333 us; speedup 1.0000x reference)
//
#include <hip/hip_runtime.h>
#include <hip/hip_fp16.h>

// out = sa*sb * (x @ q_b) @ q_a^T + bias
// Round 17: GEMM1 "full-N": BM=128 BN=512(=RANK) BK=32 SK=8 -> grid 512,
// NT=16 => 32 tile-generations/CU (half of every prior config; the R5/R6/
// R10/R15-fitted law says per-CU time = gens x ~3300cyc). x staged EXACTLY
// once (134 MB); qbt re-reads L2-served (each XCD pinned to one z-chunk,
// 512 KB slice). Single-buf 48 KB LDS, 2-res, R10 stage/fragment code.
// GEMM2 + fused reduce/cvt unchanged. R10 GEMM1 kept as small-ws fallback.

#define M_TOT 8192
#define N_OUT 4096
#define K_IN  4096
#define RANK  512

typedef _Float16 f16x8 __attribute__((ext_vector_type(8)));
typedef float f32x4 __attribute__((ext_vector_type(4)));

#define WAIT_VM0() asm volatile("s_waitcnt vmcnt(0)" ::: "memory")
#define WAIT_VM4() asm volatile("s_waitcnt vmcnt(4)" ::: "memory")
#define WAIT_VM8() asm volatile("s_waitcnt vmcnt(8)" ::: "memory")
#define BARRIER() do { __builtin_amdgcn_s_barrier(); __builtin_amdgcn_sched_barrier(0); } while (0)

__device__ __forceinline__ void gload_lds16(const void* g, void* l) {
  __builtin_amdgcn_global_load_lds(
      (const __attribute__((address_space(1))) unsigned int*)g,
      (__attribute__((address_space(3))) unsigned int*)l, 16, 0, 0);
}

// ---- transpose q_b [K_IN][RANK] i32 -> qbt [RANK][K_IN] fp16 ----
__global__ void k_transpose_qb(const int* __restrict__ qb, __half* __restrict__ qbt) {
  __shared__ __half tile[32][33];
  int tx = threadIdx.x & 31, ty = threadIdx.x >> 5;
  int k0 = blockIdx.x * 32, r0 = blockIdx.y * 32;
#pragma unroll
  for (int j = 0; j < 4; ++j)
    tile[ty + j * 8][tx] = __float2half_rn((float)qb[(size_t)(k0 + ty + j * 8) * RANK + r0 + tx]);
  __syncthreads();
#pragma unroll
  for (int j = 0; j < 4; ++j)
    qbt[(size_t)(r0 + ty + j * 8) * K_IN + k0 + tx] = tile[tx][ty + j * 8];
}

// ---- GEMM1 full-N (SK=8): P[z] = x[:,z-chunk] @ qbt[:,z-chunk]^T ----
// BM=128 BN=512 BK=32, 512 thr = 8 waves (2m x 4n), wave 64x128, acc[4][8].
// LDS: A f32 128x32 (16KB, 8-slot XOR) + B f16 512x32 (32KB, paired-row XOR)
// single-buffered = 48 KB -> 2 blocks/CU. stage -> sync -> compute -> sync.
// xcd = z (qbt z-slice 512KB L2-hot per XCD); 6 gload_lds/thread/tile.
__global__ __launch_bounds__(512, 2) void k_gemm1w(
    const float* __restrict__ X, const __half* __restrict__ Bt,
    __half* __restrict__ P) {
  __shared__ __align__(16) uint4 lds[3072];  // [0,1024)=A f32, [1024,3072)=B f16
  const int tid = threadIdx.x;
  const int lane = tid & 63, wid = tid >> 6;
  const int wm = wid & 1, wn = wid >> 1;          // 2m x 4n
  const int blk = blockIdx.x;
  const int z = blk & 7, m_t = blk >> 3;          // z 0..7, m_t 0..63
  const int m0 = m_t * 128;
  const int kbeg = z * (K_IN / 8);                // 512-col chunk
  const int fr = lane & 15, fq = lane >> 4;

  f32x4 acc[4][8] = {};

  const int NT = (K_IN / 8) / 32;  // 16
  for (int t = 0; t < NT; ++t) {
    const int k0 = kbeg + t * 32;
    // A: 128 rows x 8 f32-slots; phys d -> row d>>3, slot (d&7)^(row&7)
#pragma unroll
    for (int c = 0; c < 2; ++c) {
      int d = tid + 512 * c;
      int r = d >> 3, s = (d & 7) ^ (r & 7);
      gload_lds16(X + (size_t)(m0 + r) * K_IN + k0 + s * 4, &lds[d]);
    }
    // B: 256 pair-rows x 8 f16-slots (paired-row XOR); rows 0..511
#pragma unroll
    for (int c = 0; c < 4; ++c) {
      int d = tid + 512 * c;
      int p = d >> 3, u = (d & 7) ^ (p & 7);
      gload_lds16(Bt + (size_t)(2 * p + (u >> 2)) * K_IN + k0 + (u & 3) * 8,
                  &lds[1024 + d]);
    }
    __syncthreads();   // drains vmcnt(0) (compiler) - proven R6/R15 pattern
    f16x8 a[4], b[8];
#pragma unroll
    for (int mi = 0; mi < 4; ++mi) {
      int r = wm * 64 + mi * 16 + fr;
      f32x4 u0 = *(const f32x4*)&lds[r * 8 + ((fq * 2) ^ (r & 7))];
      f32x4 u1 = *(const f32x4*)&lds[r * 8 + ((fq * 2 + 1) ^ (r & 7))];
      union { __half2 h[4]; f16x8 v; } pa;
      pa.h[0] = __floats2half2_rn(u0[0], u0[1]);
      pa.h[1] = __floats2half2_rn(u0[2], u0[3]);
      pa.h[2] = __floats2half2_rn(u1[0], u1[1]);
      pa.h[3] = __floats2half2_rn(u1[2], u1[3]);
      a[mi] = pa.v;
    }
#pragma unroll
    for (int ni = 0; ni < 8; ++ni) {
      int r = wn * 128 + ni * 16 + fr;
      int p = r >> 1;
      b[ni] = *(const f16x8*)&lds[1024 + p * 8 + ((((r & 1) << 2) | fq) ^ (p & 7))];
    }
#pragma unroll
    for (int mi = 0; mi < 4; ++mi)
#pragma unroll
      for (int ni = 0; ni < 8; ++ni)
        acc[mi][ni] = __builtin_amdgcn_mfma_f32_16x16x32_f16(a[mi], b[ni], acc[mi][ni], 0, 0, 0);
    __syncthreads();
  }

  __half* Pz = P + (size_t)z * M_TOT * RANK;
#pragma unroll
  for (int mi = 0; mi < 4; ++mi)
#pragma unroll
    for (int ni = 0; ni < 8; ++ni) {
      int col = wn * 128 + ni * 16 + fr;
      int rbase = m0 + wm * 64 + mi * 16 + fq * 4;
#pragma unroll
      for (int j = 0; j < 4; ++j)
        Pz[(size_t)(rbase + j) * RANK + col] = __float2half_rn(acc[mi][ni][j]);
    }
}

// ---- GEMM1 fallback (R10 verbatim, SK=4) for small workspace ----
__global__ __launch_bounds__(512, 4) void k_gemm1v(
    const float* __restrict__ X, const __half* __restrict__ Bt,
    __half* __restrict__ P) {
  __shared__ __align__(16) uint4 lds[2][2048];
  const int tid = threadIdx.x;
  const int lane = tid & 63, wid = tid >> 6;
  const int wm = wid & 1, wn = wid >> 1;
  const int blk = blockIdx.x;
  const int xcd = blk & 7, m_t = blk >> 3;
  const int z = xcd >> 1, n_t = xcd & 1;
  const int m0 = m_t * 128, n0 = n_t * 256;
  const int kbeg = z * (K_IN / 4);
  const int fr = lane & 15, fq = lane >> 4;

  f32x4 acc[4][4] = {};

  auto stage = [&](int kt, int buf) {
#pragma unroll
    for (int c = 0; c < 2; ++c) {
      int d = tid + 512 * c;
      int r = d >> 3, s = (d & 7) ^ (r & 7);
      gload_lds16(X + (size_t)(m0 + r) * K_IN + kbeg + kt * 32 + s * 4, &lds[buf][d]);
    }
#pragma unroll
    for (int c = 0; c < 2; ++c) {
      int d = tid + 512 * c;
      int p = d >> 3, u = (d & 7) ^ (p & 7);
      gload_lds16(Bt + (size_t)(n0 + 2 * p + (u >> 2)) * K_IN + kbeg + kt * 32 + (u & 3) * 8,
                  &lds[buf][1024 + d]);
    }
  };

  stage(0, 0);
  stage(1, 1);
  WAIT_VM4();
  BARRIER();

  const int NT = (K_IN / 4) / 32;
  for (int t = 0; t < NT; ++t) {
    const uint4* Ab = &lds[t & 1][0];
    const uint4* Bb = &lds[t & 1][1024];
    f16x8 a[4], b[4];
#pragma unroll
    for (int mi = 0; mi < 4; ++mi) {
      int r = wm * 64 + mi * 16 + fr;
      f32x4 u0 = *(const f32x4*)&Ab[r * 8 + ((fq * 2) ^ (r & 7))];
      f32x4 u1 = *(const f32x4*)&Ab[r * 8 + ((fq * 2 + 1) ^ (r & 7))];
      union { __half2 h[4]; f16x8 v; } pa;
      pa.h[0] = __floats2half2_rn(u0[0], u0[1]);
      pa.h[1] = __floats2half2_rn(u0[2], u0[3]);
      pa.h[2] = __floats2half2_rn(u1[0], u1[1]);
      pa.h[3] = __floats2half2_rn(u1[2], u1[3]);
      a[mi] = pa.v;
    }
#pragma unroll
    for (int ni = 0; ni < 4; ++ni) {
      int r = wn * 64 + ni * 16 + fr;
      int p = r >> 1;
      b[ni] = *(const f16x8*)&Bb[p * 8 + ((((r & 1) << 2) | fq) ^ (p & 7))];
    }
#pragma unroll
    for (int mi = 0; mi < 4; ++mi)
#pragma unroll
      for (int ni = 0; ni < 4; ++ni)
        acc[mi][ni] = __builtin_amdgcn_mfma_f32_16x16x32_f16(a[mi], b[ni], acc[mi][ni], 0, 0, 0);

    if (t == NT - 1) break;
    BARRIER();
    if (t + 2 < NT) {
      stage(t + 2, t & 1);
      WAIT_VM4();
    } else {
      WAIT_VM0();
    }
    BARRIER();
  }

  __half* Pz = P + (size_t)z * M_TOT * RANK;
#pragma unroll
  for (int mi = 0; mi < 4; ++mi)
#pragma unroll
    for (int ni = 0; ni < 4; ++ni) {
      int col = n0 + wn * 64 + ni * 16 + fr;
      int rbase = m0 + wm * 64 + mi * 16 + fq * 4;
#pragma unroll
      for (int j = 0; j < 4; ++j)
        Pz[(size_t)(rbase + j) * RANK + col] = __float2half_rn(acc[mi][ni][j]);
    }
}

// ---- fused: t = f16(sum_z P[z])  AND  qa_h = f16(qa) ----
template <int SK>
__global__ void k_reduce_cvt(const uint4* __restrict__ P, uint4* __restrict__ T8, int n8,
                             const int4* __restrict__ qa, ushort4* __restrict__ qh, int nq4) {
  int b = blockIdx.x;
  int nred = n8 / 256;
  if (b < nred) {
    int i = b * 256 + threadIdx.x;
    float2 f[4] = {};
#pragma unroll
    for (int zz = 0; zz < SK; ++zz) {
      uint4 v = P[(size_t)zz * n8 + i];
      const __half2* h = (const __half2*)&v;
#pragma unroll
      for (int j = 0; j < 4; ++j) {
        float2 g = __half22float2(h[j]);
        f[j].x += g.x; f[j].y += g.y;
      }
    }
    uint4 r;
    __half2* o = (__half2*)&r;
#pragma unroll
    for (int j = 0; j < 4; ++j) o[j] = __floats2half2_rn(f[j].x, f[j].y);
    T8[i] = r;
  } else {
    int i = (b - nred) * 256 + threadIdx.x;
    if (i >= nq4) return;
    int4 v = qa[i];
    ushort4 r;
    r.x = __half_as_ushort(__float2half_rn((float)v.x));
    r.y = __half_as_ushort(__float2half_rn((float)v.y));
    r.z = __half_as_ushort(__float2half_rn((float)v.z));
    r.w = __half_as_ushort(__float2half_rn((float)v.w));
    qh[i] = r;
  }
}

// ---- GEMM2: out = t @ qa^T * scale + bias (R10 proven version, verbatim) ----
__global__ __launch_bounds__(256, 2) void k_gemm2(
    const __half* __restrict__ T, const __half* __restrict__ QA,
    const float* __restrict__ sa, const float* __restrict__ sb,
    const float* __restrict__ bias, float* __restrict__ Out) {
  __shared__ __align__(16) uint4 lds[2][2048];
  const int tid = threadIdx.x;
  const int lane = tid & 63, wid = tid >> 6, wm = wid & 1, wn = wid >> 1;
  const int flat = blockIdx.x;
  const int xcd = flat & 7, local = flat >> 3;
  const int n_t = xcd * 4 + (local & 3);
  const int m_t = local >> 2;
  const int m0 = m_t * 128, n0 = n_t * 128;
  const int fr = lane & 15, fq = lane >> 4;

  f32x4 acc[4][4] = {};

  auto stage = [&](int kt, int buf) {
#pragma unroll
    for (int c = 0; c < 4; ++c) {
      int d = tid + 256 * c;
      int r = d >> 3, s = (d & 7) ^ (r & 7);
      gload_lds16(T + (size_t)(m0 + r) * RANK + kt * 64 + s * 8, &lds[buf][d]);
    }
#pragma unroll
    for (int c = 0; c < 4; ++c) {
      int d = tid + 256 * c;
      int r = d >> 3, s = (d & 7) ^ (r & 7);
      gload_lds16(QA + (size_t)(n0 + r) * RANK + kt * 64 + s * 8, &lds[buf][1024 + d]);
    }
  };

  stage(0, 0);
  stage(1, 1);
  WAIT_VM8();
  BARRIER();

  const int NT = RANK / 64;
  for (int t = 0; t < NT; ++t) {
    const int cur = t & 1;
#pragma unroll
    for (int kk = 0; kk < 2; ++kk) {
      int s = kk * 4 + fq;
      f16x8 a[4], b[4];
#pragma unroll
      for (int mi = 0; mi < 4; ++mi) {
        int r = wm * 64 + mi * 16 + fr;
        a[mi] = *(const f16x8*)&lds[cur][r * 8 + (s ^ (r & 7))];
      }
#pragma unroll
      for (int ni = 0; ni < 4; ++ni) {
        int n = wn * 64 + ni * 16 + fr;
        b[ni] = *(const f16x8*)&lds[cur][1024 + n * 8 + (s ^ (n & 7))];
      }
#pragma unroll
      for (int mi = 0; mi < 4; ++mi)
#pragma unroll
        for (int ni = 0; ni < 4; ++ni)
          acc[mi][ni] = __builtin_amdgcn_mfma_f32_16x16x32_f16(a[mi], b[ni], acc[mi][ni], 0, 0, 0);
    }
    if (t == NT - 1) break;
    BARRIER();
    if (t + 2 < NT) {
      stage(t + 2, cur);
      WAIT_VM8();
    } else {
      WAIT_VM0();
    }
    BARRIER();
  }

  const float scale = sa[0] * sb[0];
#pragma unroll
  for (int mi = 0; mi < 4; ++mi)
#pragma unroll
    for (int ni = 0; ni < 4; ++ni) {
      int col = n0 + wn * 64 + ni * 16 + fr;
      float bv = bias[col];
      int rbase = m0 + wm * 64 + mi * 16 + fq * 4;
#pragma unroll
      for (int j = 0; j < 4; ++j)
        Out[(size_t)(rbase + j) * N_OUT + col] = acc[mi][ni][j] * scale + bv;
    }
}

extern "C" void kernel_launch(void* const* d_in, const int* in_sizes, int n_in,
                              void* d_out, int out_size, void* d_ws, size_t ws_size,
                              hipStream_t stream) {
  const float* x    = (const float*)d_in[0];
  const int*   qa   = (const int*)d_in[1];
  const int*   qb   = (const int*)d_in[2];
  const float* sa   = (const float*)d_in[3];
  const float* sb   = (const float*)d_in[4];
  const float* bias = (const float*)d_in[5];
  float* out = (float*)d_out;

  // layout: qa_h 4MB | qbt 4MB | t 8MB | part (SK x 8MB) -> 80 MiB for SK=8
  char* ws = (char*)d_ws;
  __half* qa_h = (__half*)ws;
  __half* qbt  = (__half*)(ws + (4u << 20));
  __half* t    = (__half*)(ws + (8u << 20));
  __half* part = (__half*)(ws + (16u << 20));

  dim3 tg(K_IN / 32, RANK / 32);
  k_transpose_qb<<<tg, 256, 0, stream>>>(qb, qbt);

  const int n8 = M_TOT * RANK / 8;           // 524288
  const int nq4 = N_OUT * RANK / 4;          // 524288
  const int nred = n8 / 256;                 // 2048
  const int ncvt = (nq4 + 255) / 256;        // 2048

  if (ws_size >= (80ull << 20)) {
    k_gemm1w<<<512, 512, 0, stream>>>(x, qbt, part);
    k_reduce_cvt<8><<<nred + ncvt, 256, 0, stream>>>((const uint4*)part, (uint4*)t, n8,
                                                     (const int4*)qa, (ushort4*)qa_h, nq4);
  } else {
    k_gemm1v<<<512, 512, 0, stream>>>(x, qbt, part);
    k_reduce_cvt<4><<<nred + ncvt, 256, 0, stream>>>((const uint4*)part, (uint4*)t, n8,
                                                     (const int4*)qa, (ushort4*)qa_h, nq4);
  }

  k_gemm2<<<2048, 256, 0, stream>>>(t, qa_h, sa, sb, bias, out);
}

// Round 18
// 141.395 us; speedup vs baseline: 1.0915x; 1.0915x over previous
//
#include <hip/hip_runtime.h>
#include <hip/hip_fp16.h>

// out = sa*sb * (x @ q_b) @ q_a^T + bias
// Round 18: R16 config (best, 132.5us) with ONE change: GEMM2 BK 64->32 so
// the double-buffer fits 32 KB -> 4 resident blocks/CU (residency x rate law:
// L2-served delivery scaled 15 B/cyc per resident block in gemm2; 4-res
// predicted ~45 B/cyc -> gemm2 ~30 -> ~22-26 us). All else R16 verbatim.

#define M_TOT 8192
#define N_OUT 4096
#define K_IN  4096
#define RANK  512

typedef _Float16 f16x8 __attribute__((ext_vector_type(8)));
typedef float f32x4 __attribute__((ext_vector_type(4)));

#define WAIT_VM0() asm volatile("s_waitcnt vmcnt(0)" ::: "memory")
#define WAIT_VM4() asm volatile("s_waitcnt vmcnt(4)" ::: "memory")
#define BARRIER() do { __builtin_amdgcn_s_barrier(); __builtin_amdgcn_sched_barrier(0); } while (0)

__device__ __forceinline__ void gload_lds16(const void* g, void* l) {
  __builtin_amdgcn_global_load_lds(
      (const __attribute__((address_space(1))) unsigned int*)g,
      (__attribute__((address_space(3))) unsigned int*)l, 16, 0, 0);
}

// ---- transpose q_b [K_IN][RANK] i32 -> qbt [RANK][K_IN] fp16 ----
__global__ void k_transpose_qb(const int* __restrict__ qb, __half* __restrict__ qbt) {
  __shared__ __half tile[32][33];
  int tx = threadIdx.x & 31, ty = threadIdx.x >> 5;
  int k0 = blockIdx.x * 32, r0 = blockIdx.y * 32;
#pragma unroll
  for (int j = 0; j < 4; ++j)
    tile[ty + j * 8][tx] = __float2half_rn((float)qb[(size_t)(k0 + ty + j * 8) * RANK + r0 + tx]);
  __syncthreads();
#pragma unroll
  for (int j = 0; j < 4; ++j)
    qbt[(size_t)(r0 + ty + j * 8) * K_IN + k0 + tx] = tile[tx][ty + j * 8];
}

// ---- GEMM1 (R16 verbatim): P[z] = x[:,z-chunk] @ qbt[:,z-chunk]^T ----
// BM=128 BN=256 BK=32, 512 thr = 8 waves (2m x 4n), wave 64x64, acc[4][4].
// f32-A direct gload_lds + cvt-at-read; counted vmcnt(4) two-barrier dbuf.
__global__ __launch_bounds__(512, 4) void k_gemm1v(
    const float* __restrict__ X, const __half* __restrict__ Bt,
    __half* __restrict__ P) {
  __shared__ __align__(16) uint4 lds[2][2048];  // [buf][0..1023]=A f32, [1024..2047]=B f16
  const int tid = threadIdx.x;
  const int lane = tid & 63, wid = tid >> 6;
  const int wm = wid & 1, wn = wid >> 1;          // 2m x 4n
  const int blk = blockIdx.x;
  const int xcd = blk & 7, m_t = blk >> 3;        // m_t 0..63
  const int z = xcd >> 1, n_t = xcd & 1;
  const int m0 = m_t * 128, n0 = n_t * 256;
  const int kbeg = z * (K_IN / 4);
  const int fr = lane & 15, fq = lane >> 4;

  f32x4 acc[4][4] = {};

  auto stage = [&](int kt, int buf) {
#pragma unroll
    for (int c = 0; c < 2; ++c) {
      int d = tid + 512 * c;
      int r = d >> 3, s = (d & 7) ^ (r & 7);
      gload_lds16(X + (size_t)(m0 + r) * K_IN + kbeg + kt * 32 + s * 4, &lds[buf][d]);
    }
#pragma unroll
    for (int c = 0; c < 2; ++c) {
      int d = tid + 512 * c;
      int p = d >> 3, u = (d & 7) ^ (p & 7);
      gload_lds16(Bt + (size_t)(n0 + 2 * p + (u >> 2)) * K_IN + kbeg + kt * 32 + (u & 3) * 8,
                  &lds[buf][1024 + d]);
    }
  };

  stage(0, 0);
  stage(1, 1);
  WAIT_VM4();
  BARRIER();

  const int NT = (K_IN / 4) / 32;  // 32
  for (int t = 0; t < NT; ++t) {
    const uint4* Ab = &lds[t & 1][0];
    const uint4* Bb = &lds[t & 1][1024];
    f16x8 a[4], b[4];
#pragma unroll
    for (int mi = 0; mi < 4; ++mi) {
      int r = wm * 64 + mi * 16 + fr;
      f32x4 u0 = *(const f32x4*)&Ab[r * 8 + ((fq * 2) ^ (r & 7))];
      f32x4 u1 = *(const f32x4*)&Ab[r * 8 + ((fq * 2 + 1) ^ (r & 7))];
      union { __half2 h[4]; f16x8 v; } pa;
      pa.h[0] = __floats2half2_rn(u0[0], u0[1]);
      pa.h[1] = __floats2half2_rn(u0[2], u0[3]);
      pa.h[2] = __floats2half2_rn(u1[0], u1[1]);
      pa.h[3] = __floats2half2_rn(u1[2], u1[3]);
      a[mi] = pa.v;
    }
#pragma unroll
    for (int ni = 0; ni < 4; ++ni) {
      int r = wn * 64 + ni * 16 + fr;
      int p = r >> 1;
      b[ni] = *(const f16x8*)&Bb[p * 8 + ((((r & 1) << 2) | fq) ^ (p & 7))];
    }
#pragma unroll
    for (int mi = 0; mi < 4; ++mi)
#pragma unroll
      for (int ni = 0; ni < 4; ++ni)
        acc[mi][ni] = __builtin_amdgcn_mfma_f32_16x16x32_f16(a[mi], b[ni], acc[mi][ni], 0, 0, 0);

    if (t == NT - 1) break;
    BARRIER();
    if (t + 2 < NT) {
      stage(t + 2, t & 1);
      WAIT_VM4();
    } else {
      WAIT_VM0();
    }
    BARRIER();
  }

  __half* Pz = P + (size_t)z * M_TOT * RANK;
#pragma unroll
  for (int mi = 0; mi < 4; ++mi)
#pragma unroll
    for (int ni = 0; ni < 4; ++ni) {
      int col = n0 + wn * 64 + ni * 16 + fr;
      int rbase = m0 + wm * 64 + mi * 16 + fq * 4;
#pragma unroll
      for (int j = 0; j < 4; ++j)
        Pz[(size_t)(rbase + j) * RANK + col] = __float2half_rn(acc[mi][ni][j]);
    }
}

// ---- fused: t = f16(sum_z P[z])  AND  qa_h = f16(qa)  (R16 verbatim) ----
__global__ void k_reduce_cvt(const uint4* __restrict__ P, uint4* __restrict__ T8, int n8,
                             const int4* __restrict__ qa, ushort4* __restrict__ qh, int nq4) {
  int b = blockIdx.x;
  int nred = n8 / 256;
  if (b < nred) {
    int i = b * 256 + threadIdx.x;
    float2 f[4] = {};
#pragma unroll
    for (int zz = 0; zz < 4; ++zz) {
      uint4 v = P[(size_t)zz * n8 + i];
      const __half2* h = (const __half2*)&v;
#pragma unroll
      for (int j = 0; j < 4; ++j) {
        float2 g = __half22float2(h[j]);
        f[j].x += g.x; f[j].y += g.y;
      }
    }
    uint4 r;
    __half2* o = (__half2*)&r;
#pragma unroll
    for (int j = 0; j < 4; ++j) o[j] = __floats2half2_rn(f[j].x, f[j].y);
    T8[i] = r;
  } else {
    int i = (b - nred) * 256 + threadIdx.x;
    if (i >= nq4) return;
    int4 v = qa[i];
    ushort4 r;
    r.x = __half_as_ushort(__float2half_rn((float)v.x));
    r.y = __half_as_ushort(__float2half_rn((float)v.y));
    r.z = __half_as_ushort(__float2half_rn((float)v.z));
    r.w = __half_as_ushort(__float2half_rn((float)v.w));
    qh[i] = r;
  }
}

// ---- GEMM2 (4-res): out = t @ qa^T * scale + bias ----
// BM=128 BN=128 BK=32, 256 thr, 4 waves (2x2), wave 64x64, acc[4][4], NT=16.
// LDS dbuf 2 x 16 KB = 32 KB -> 4 blocks/CU. Counted vmcnt(4) two-barrier.
// 4-slot rows, XOR (r&3) swizzle (stage + read consistent, R14-verified).
__global__ __launch_bounds__(256, 4) void k_gemm2c(
    const __half* __restrict__ T, const __half* __restrict__ QA,
    const float* __restrict__ sa, const float* __restrict__ sb,
    const float* __restrict__ bias, float* __restrict__ Out) {
  __shared__ __align__(16) uint4 lds[2][1024];  // [buf][0..511]=A, [512..1023]=B
  const int tid = threadIdx.x;
  const int lane = tid & 63, wid = tid >> 6, wm = wid & 1, wn = wid >> 1;
  const int flat = blockIdx.x;
  const int xcd = flat & 7, local = flat >> 3;
  const int n_t = xcd * 4 + (local & 3);
  const int m_t = local >> 2;
  const int m0 = m_t * 128, n0 = n_t * 128;
  const int fr = lane & 15, fq = lane >> 4;

  f32x4 acc[4][4] = {};

  auto stage = [&](int kt, int buf) {
#pragma unroll
    for (int c = 0; c < 2; ++c) {
      int d = tid + 256 * c;
      int r = d >> 2, s = (d & 3) ^ (r & 3);
      gload_lds16(T + (size_t)(m0 + r) * RANK + kt * 32 + s * 8, &lds[buf][d]);
    }
#pragma unroll
    for (int c = 0; c < 2; ++c) {
      int d = tid + 256 * c;
      int r = d >> 2, s = (d & 3) ^ (r & 3);
      gload_lds16(QA + (size_t)(n0 + r) * RANK + kt * 32 + s * 8, &lds[buf][512 + d]);
    }
  };

  stage(0, 0);
  stage(1, 1);
  WAIT_VM4();   // tile 0's 4 loads done (tile 1's 4 in flight)
  BARRIER();

  const int NT = RANK / 32;  // 16
  for (int t = 0; t < NT; ++t) {
    const uint4* Ab = &lds[t & 1][0];
    const uint4* Bb = &lds[t & 1][512];
    f16x8 a[4], b[4];
#pragma unroll
    for (int mi = 0; mi < 4; ++mi) {
      int r = wm * 64 + mi * 16 + fr;
      a[mi] = *(const f16x8*)&Ab[r * 4 + (fq ^ (r & 3))];
    }
#pragma unroll
    for (int ni = 0; ni < 4; ++ni) {
      int n = wn * 64 + ni * 16 + fr;
      b[ni] = *(const f16x8*)&Bb[n * 4 + (fq ^ (n & 3))];
    }
#pragma unroll
    for (int mi = 0; mi < 4; ++mi)
#pragma unroll
      for (int ni = 0; ni < 4; ++ni)
        acc[mi][ni] = __builtin_amdgcn_mfma_f32_16x16x32_f16(a[mi], b[ni], acc[mi][ni], 0, 0, 0);

    if (t == NT - 1) break;
    BARRIER();
    if (t + 2 < NT) {
      stage(t + 2, t & 1);
      WAIT_VM4();                  // t+1's 4 loads retired; t+2's in flight
    } else {
      WAIT_VM0();
    }
    BARRIER();
  }

  const float scale = sa[0] * sb[0];
#pragma unroll
  for (int mi = 0; mi < 4; ++mi)
#pragma unroll
    for (int ni = 0; ni < 4; ++ni) {
      int col = n0 + wn * 64 + ni * 16 + fr;
      float bv = bias[col];
      int rbase = m0 + wm * 64 + mi * 16 + fq * 4;
#pragma unroll
      for (int j = 0; j < 4; ++j)
        Out[(size_t)(rbase + j) * N_OUT + col] = acc[mi][ni][j] * scale + bv;
    }
}

extern "C" void kernel_launch(void* const* d_in, const int* in_sizes, int n_in,
                              void* d_out, int out_size, void* d_ws, size_t ws_size,
                              hipStream_t stream) {
  const float* x    = (const float*)d_in[0];
  const int*   qa   = (const int*)d_in[1];
  const int*   qb   = (const int*)d_in[2];
  const float* sa   = (const float*)d_in[3];
  const float* sb   = (const float*)d_in[4];
  const float* bias = (const float*)d_in[5];
  float* out = (float*)d_out;

  // layout: qa_h 4MB | qbt 4MB | t 8MB | part 32MB  = 48 MiB
  char* ws = (char*)d_ws;
  __half* qa_h = (__half*)ws;
  __half* qbt  = (__half*)(ws + (4u << 20));
  __half* t    = (__half*)(ws + (8u << 20));
  __half* part = (__half*)(ws + (16u << 20));

  dim3 tg(K_IN / 32, RANK / 32);
  k_transpose_qb<<<tg, 256, 0, stream>>>(qb, qbt);

  k_gemm1v<<<512, 512, 0, stream>>>(x, qbt, part);

  const int n8 = M_TOT * RANK / 8;           // 524288
  const int nq4 = N_OUT * RANK / 4;          // 524288
  const int nred = n8 / 256;                 // 2048
  const int ncvt = (nq4 + 255) / 256;        // 2048
  k_reduce_cvt<<<nred + ncvt, 256, 0, stream>>>((const uint4*)part, (uint4*)t, n8,
                                                (const int4*)qa, (ushort4*)qa_h, nq4);

  k_gemm2c<<<2048, 256, 0, stream>>>(t, qa_h, sa, sb, bias, out);
}

// Round 19
// 132.143 us; speedup vs baseline: 1.1679x; 1.0700x over previous
//
#include <hip/hip_runtime.h>
#include <hip/hip_fp16.h>

// out = sa*sb * (x @ q_b) @ q_a^T + bias
// Round 19: REVERT to R16 (session best, 132.5 us). R18's GEMM2 BK=32/4-res
// regressed (+9 us): for L2-resident streams, per-generation overhead (not
// delivery rate) is marginal, so BK=64/2-res is balanced.
// GEMM1: f32-A direct gload_lds + cvt-at-read, counted vmcnt(4) dbuf, SK=4.
// GEMM2: counted vmcnt(8) dbuf 128x128 BK=64. reduce fused with qa-convert.

#define M_TOT 8192
#define N_OUT 4096
#define K_IN  4096
#define RANK  512

typedef _Float16 f16x8 __attribute__((ext_vector_type(8)));
typedef float f32x4 __attribute__((ext_vector_type(4)));

#define WAIT_VM0() asm volatile("s_waitcnt vmcnt(0)" ::: "memory")
#define WAIT_VM4() asm volatile("s_waitcnt vmcnt(4)" ::: "memory")
#define WAIT_VM8() asm volatile("s_waitcnt vmcnt(8)" ::: "memory")
#define BARRIER() do { __builtin_amdgcn_s_barrier(); __builtin_amdgcn_sched_barrier(0); } while (0)

__device__ __forceinline__ void gload_lds16(const void* g, void* l) {
  __builtin_amdgcn_global_load_lds(
      (const __attribute__((address_space(1))) unsigned int*)g,
      (__attribute__((address_space(3))) unsigned int*)l, 16, 0, 0);
}

// ---- transpose q_b [K_IN][RANK] i32 -> qbt [RANK][K_IN] fp16 ----
__global__ void k_transpose_qb(const int* __restrict__ qb, __half* __restrict__ qbt) {
  __shared__ __half tile[32][33];
  int tx = threadIdx.x & 31, ty = threadIdx.x >> 5;
  int k0 = blockIdx.x * 32, r0 = blockIdx.y * 32;
#pragma unroll
  for (int j = 0; j < 4; ++j)
    tile[ty + j * 8][tx] = __float2half_rn((float)qb[(size_t)(k0 + ty + j * 8) * RANK + r0 + tx]);
  __syncthreads();
#pragma unroll
  for (int j = 0; j < 4; ++j)
    qbt[(size_t)(r0 + ty + j * 8) * K_IN + k0 + tx] = tile[tx][ty + j * 8];
}

// ---- GEMM1: P[z] = x[:,z-chunk] @ qbt[:,z-chunk]^T, f32-A direct DMA ----
// BM=128 BN=256 BK=32, 512 thr = 8 waves (2m x 4n), wave 64x64, acc[4][4].
// LDS per buf: A 128x32 f32 (16KB, 8-slot XOR rows) + B 256x32 f16 (16KB,
// paired-row XOR). dbuf 64 KB. 4 gload_lds/thread/tile, counted vmcnt(4).
__global__ __launch_bounds__(512, 4) void k_gemm1v(
    const float* __restrict__ X, const __half* __restrict__ Bt,
    __half* __restrict__ P) {
  __shared__ __align__(16) uint4 lds[2][2048];  // [buf][0..1023]=A f32, [1024..2047]=B f16
  const int tid = threadIdx.x;
  const int lane = tid & 63, wid = tid >> 6;
  const int wm = wid & 1, wn = wid >> 1;          // 2m x 4n
  const int blk = blockIdx.x;
  const int xcd = blk & 7, m_t = blk >> 3;        // m_t 0..63
  const int z = xcd >> 1, n_t = xcd & 1;
  const int m0 = m_t * 128, n0 = n_t * 256;
  const int kbeg = z * (K_IN / 4);
  const int fr = lane & 15, fq = lane >> 4;

  f32x4 acc[4][4] = {};

  auto stage = [&](int kt, int buf) {
#pragma unroll
    for (int c = 0; c < 2; ++c) {
      int d = tid + 512 * c;
      int r = d >> 3, s = (d & 7) ^ (r & 7);
      gload_lds16(X + (size_t)(m0 + r) * K_IN + kbeg + kt * 32 + s * 4, &lds[buf][d]);
    }
#pragma unroll
    for (int c = 0; c < 2; ++c) {
      int d = tid + 512 * c;
      int p = d >> 3, u = (d & 7) ^ (p & 7);
      gload_lds16(Bt + (size_t)(n0 + 2 * p + (u >> 2)) * K_IN + kbeg + kt * 32 + (u & 3) * 8,
                  &lds[buf][1024 + d]);
    }
  };

  stage(0, 0);
  stage(1, 1);
  WAIT_VM4();   // tile 0's 4 loads done (tile 1's 4 in flight)
  BARRIER();

  const int NT = (K_IN / 4) / 32;  // 32
  for (int t = 0; t < NT; ++t) {
    const uint4* Ab = &lds[t & 1][0];
    const uint4* Bb = &lds[t & 1][1024];
    f16x8 a[4], b[4];
#pragma unroll
    for (int mi = 0; mi < 4; ++mi) {
      int r = wm * 64 + mi * 16 + fr;
      f32x4 u0 = *(const f32x4*)&Ab[r * 8 + ((fq * 2) ^ (r & 7))];
      f32x4 u1 = *(const f32x4*)&Ab[r * 8 + ((fq * 2 + 1) ^ (r & 7))];
      union { __half2 h[4]; f16x8 v; } pa;
      pa.h[0] = __floats2half2_rn(u0[0], u0[1]);
      pa.h[1] = __floats2half2_rn(u0[2], u0[3]);
      pa.h[2] = __floats2half2_rn(u1[0], u1[1]);
      pa.h[3] = __floats2half2_rn(u1[2], u1[3]);
      a[mi] = pa.v;
    }
#pragma unroll
    for (int ni = 0; ni < 4; ++ni) {
      int r = wn * 64 + ni * 16 + fr;
      int p = r >> 1;
      b[ni] = *(const f16x8*)&Bb[p * 8 + ((((r & 1) << 2) | fq) ^ (p & 7))];
    }
#pragma unroll
    for (int mi = 0; mi < 4; ++mi)
#pragma unroll
      for (int ni = 0; ni < 4; ++ni)
        acc[mi][ni] = __builtin_amdgcn_mfma_f32_16x16x32_f16(a[mi], b[ni], acc[mi][ni], 0, 0, 0);

    if (t == NT - 1) break;
    BARRIER();                       // all waves done reading buf (t+1 parity)
    if (t + 2 < NT) {
      stage(t + 2, t & 1);
      WAIT_VM4();                    // tile t+1's 4 loads landed
    } else {
      WAIT_VM0();
    }
    BARRIER();
  }

  __half* Pz = P + (size_t)z * M_TOT * RANK;
#pragma unroll
  for (int mi = 0; mi < 4; ++mi)
#pragma unroll
    for (int ni = 0; ni < 4; ++ni) {
      int col = n0 + wn * 64 + ni * 16 + fr;
      int rbase = m0 + wm * 64 + mi * 16 + fq * 4;
#pragma unroll
      for (int j = 0; j < 4; ++j)
        Pz[(size_t)(rbase + j) * RANK + col] = __float2half_rn(acc[mi][ni][j]);
    }
}

// ---- fused: t = f16(sum_z P[z])  AND  qa_h = f16(qa) ----
// blocks [0, n8/256): reduce; blocks [n8/256, +nq4/256): qa convert.
__global__ void k_reduce_cvt(const uint4* __restrict__ P, uint4* __restrict__ T8, int n8,
                             const int4* __restrict__ qa, ushort4* __restrict__ qh, int nq4) {
  int b = blockIdx.x;
  int nred = n8 / 256;
  if (b < nred) {
    int i = b * 256 + threadIdx.x;
    float2 f[4] = {};
#pragma unroll
    for (int zz = 0; zz < 4; ++zz) {
      uint4 v = P[(size_t)zz * n8 + i];
      const __half2* h = (const __half2*)&v;
#pragma unroll
      for (int j = 0; j < 4; ++j) {
        float2 g = __half22float2(h[j]);
        f[j].x += g.x; f[j].y += g.y;
      }
    }
    uint4 r;
    __half2* o = (__half2*)&r;
#pragma unroll
    for (int j = 0; j < 4; ++j) o[j] = __floats2half2_rn(f[j].x, f[j].y);
    T8[i] = r;
  } else {
    int i = (b - nred) * 256 + threadIdx.x;
    if (i >= nq4) return;
    int4 v = qa[i];
    ushort4 r;
    r.x = __half_as_ushort(__float2half_rn((float)v.x));
    r.y = __half_as_ushort(__float2half_rn((float)v.y));
    r.z = __half_as_ushort(__float2half_rn((float)v.z));
    r.w = __half_as_ushort(__float2half_rn((float)v.w));
    qh[i] = r;
  }
}

// ---- GEMM2: out = t @ qa^T * scale + bias (proven best: BK=64, 2-res) ----
__global__ __launch_bounds__(256, 2) void k_gemm2(
    const __half* __restrict__ T, const __half* __restrict__ QA,
    const float* __restrict__ sa, const float* __restrict__ sb,
    const float* __restrict__ bias, float* __restrict__ Out) {
  __shared__ __align__(16) uint4 lds[2][2048];
  const int tid = threadIdx.x;
  const int lane = tid & 63, wid = tid >> 6, wm = wid & 1, wn = wid >> 1;
  const int flat = blockIdx.x;
  const int xcd = flat & 7, local = flat >> 3;
  const int n_t = xcd * 4 + (local & 3);
  const int m_t = local >> 2;
  const int m0 = m_t * 128, n0 = n_t * 128;
  const int fr = lane & 15, fq = lane >> 4;

  f32x4 acc[4][4] = {};

  auto stage = [&](int kt, int buf) {
#pragma unroll
    for (int c = 0; c < 4; ++c) {
      int d = tid + 256 * c;
      int r = d >> 3, s = (d & 7) ^ (r & 7);
      gload_lds16(T + (size_t)(m0 + r) * RANK + kt * 64 + s * 8, &lds[buf][d]);
    }
#pragma unroll
    for (int c = 0; c < 4; ++c) {
      int d = tid + 256 * c;
      int r = d >> 3, s = (d & 7) ^ (r & 7);
      gload_lds16(QA + (size_t)(n0 + r) * RANK + kt * 64 + s * 8, &lds[buf][1024 + d]);
    }
  };

  stage(0, 0);
  stage(1, 1);
  WAIT_VM8();
  BARRIER();

  const int NT = RANK / 64;
  for (int t = 0; t < NT; ++t) {
    const int cur = t & 1;
#pragma unroll
    for (int kk = 0; kk < 2; ++kk) {
      int s = kk * 4 + fq;
      f16x8 a[4], b[4];
#pragma unroll
      for (int mi = 0; mi < 4; ++mi) {
        int r = wm * 64 + mi * 16 + fr;
        a[mi] = *(const f16x8*)&lds[cur][r * 8 + (s ^ (r & 7))];
      }
#pragma unroll
      for (int ni = 0; ni < 4; ++ni) {
        int n = wn * 64 + ni * 16 + fr;
        b[ni] = *(const f16x8*)&lds[cur][1024 + n * 8 + (s ^ (n & 7))];
      }
#pragma unroll
      for (int mi = 0; mi < 4; ++mi)
#pragma unroll
        for (int ni = 0; ni < 4; ++ni)
          acc[mi][ni] = __builtin_amdgcn_mfma_f32_16x16x32_f16(a[mi], b[ni], acc[mi][ni], 0, 0, 0);
    }
    if (t == NT - 1) break;
    BARRIER();
    if (t + 2 < NT) {
      stage(t + 2, cur);
      WAIT_VM8();
    } else {
      WAIT_VM0();
    }
    BARRIER();
  }

  const float scale = sa[0] * sb[0];
#pragma unroll
  for (int mi = 0; mi < 4; ++mi)
#pragma unroll
    for (int ni = 0; ni < 4; ++ni) {
      int col = n0 + wn * 64 + ni * 16 + fr;
      float bv = bias[col];
      int rbase = m0 + wm * 64 + mi * 16 + fq * 4;
#pragma unroll
      for (int j = 0; j < 4; ++j)
        Out[(size_t)(rbase + j) * N_OUT + col] = acc[mi][ni][j] * scale + bv;
    }
}

extern "C" void kernel_launch(void* const* d_in, const int* in_sizes, int n_in,
                              void* d_out, int out_size, void* d_ws, size_t ws_size,
                              hipStream_t stream) {
  const float* x    = (const float*)d_in[0];
  const int*   qa   = (const int*)d_in[1];
  const int*   qb   = (const int*)d_in[2];
  const float* sa   = (const float*)d_in[3];
  const float* sb   = (const float*)d_in[4];
  const float* bias = (const float*)d_in[5];
  float* out = (float*)d_out;

  // layout: qa_h 4MB | qbt 4MB | t 8MB | part 32MB  = 48 MiB
  char* ws = (char*)d_ws;
  __half* qa_h = (__half*)ws;
  __half* qbt  = (__half*)(ws + (4u << 20));
  __half* t    = (__half*)(ws + (8u << 20));
  __half* part = (__half*)(ws + (16u << 20));

  dim3 tg(K_IN / 32, RANK / 32);
  k_transpose_qb<<<tg, 256, 0, stream>>>(qb, qbt);

  k_gemm1v<<<512, 512, 0, stream>>>(x, qbt, part);

  const int n8 = M_TOT * RANK / 8;           // 524288
  const int nq4 = N_OUT * RANK / 4;          // 524288
  const int nred = n8 / 256;                 // 2048
  const int ncvt = (nq4 + 255) / 256;        // 2048
  k_reduce_cvt<<<nred + ncvt, 256, 0, stream>>>((const uint4*)part, (uint4*)t, n8,
                                                (const int4*)qa, (ushort4*)qa_h, nq4);

  k_gemm2<<<2048, 256, 0, stream>>>(t, qa_h, sa, sb, bias, out);
}